// Round 1
// baseline (141.466 us; speedup 1.0000x reference)
//
#include <hip/hip_runtime.h>
#include <math.h>

#define PI_F 3.14159f

// ---------------- Kernel A: p = relu(para_code @ W_c + b_c) ----------------
// grid 16 = b(4) x col-chunk(4), block 64. Each thread owns one output column.
__global__ __launch_bounds__(64) void mlp_p_kernel(
    const float* __restrict__ para_code,
    const float* __restrict__ W_c,
    const float* __restrict__ b_c,
    float* __restrict__ p_ws) {
  int b = blockIdx.x >> 2, ch = blockIdx.x & 3;
  __shared__ float pc[256];
  for (int i = threadIdx.x; i < 256; i += 64) pc[i] = para_code[b * 256 + i];
  __syncthreads();
  int j = ch * 64 + threadIdx.x;
  float acc = b_c[j];
#pragma unroll 4
  for (int k = 0; k < 256; ++k) acc = fmaf(pc[k], W_c[k * 256 + j], acc);
  p_ws[b * 256 + j] = fmaxf(acc, 0.0f);
}

// ---------------- Kernel B: heads (scale / cos / sin / t0 / t1) ----------------
// grid 16 = d-chunk of 16, block 64; thread t -> (d' = t>>2, b = t&3).
// par_ws layout: [0,1024) scale, [1024) cos, [2048) sin, [3072) t0, [4096) t1.
__global__ __launch_bounds__(64) void mlp_heads_kernel(
    const float* __restrict__ p_ws,
    const float* __restrict__ W_s, const float* __restrict__ b_s,
    const float* __restrict__ W_r, const float* __restrict__ b_r,
    const float* __restrict__ W_t, const float* __restrict__ b_t,
    float* __restrict__ par_ws) {
  __shared__ float pl[4][257];  // +1 pad: lanes b=0..3 read (b*257+k) -> distinct banks
  for (int i = threadIdx.x; i < 1024; i += 64) pl[i >> 8][i & 255] = p_ws[i];
  __syncthreads();
  int t = threadIdx.x;
  int dp = t >> 2, b = t & 3;
  int d = blockIdx.x * 16 + dp;
  float sa = b_s[d];
  float ra = b_r[d];
  float2 tb2 = ((const float2*)b_t)[d];
  float ta = tb2.x, tbv = tb2.y;
  const float2* W_t2 = (const float2*)W_t;
#pragma unroll 4
  for (int k = 0; k < 256; ++k) {
    float pk = pl[b][k];
    sa = fmaf(pk, W_s[k * 256 + d], sa);
    ra = fmaf(pk, W_r[k * 256 + d], ra);
    float2 wt = W_t2[k * 256 + d];
    ta = fmaf(pk, wt.x, ta);
    tbv = fmaf(pk, wt.y, tbv);
  }
  int od = b * 256 + d;
  float scl = 2.0f / (1.0f + expf(-sa));
  float ang = tanhf(ra) * PI_F;
  par_ws[od] = scl;
  par_ws[1024 + od] = cosf(ang);
  par_ws[2048 + od] = sinf(ang);
  par_ws[3072 + od] = tanhf(ta);
  par_ws[4096 + od] = tanhf(tbv);
}

// ---------------- Kernel C: warp + trilinear grid-sample ----------------
// grid 1024 = b*256+d, block 256. Stage slices z0,z0+1 (16KB each) in LDS with
// XOR bank swizzle; each thread computes 16 output points (4 float4 stores).
__global__ __launch_bounds__(256) void warp_sample_kernel(
    const float* __restrict__ fm,
    const float* __restrict__ par_ws,
    float* __restrict__ out) {
  int bd = blockIdx.x;
  int d = bd & 255;
  int b = bd >> 8;
  __shared__ float sm[2][4096];

  // z setup — mirror reference formulas
  float gzc = 2.0f * (d * (1.0f / 255.0f)) - 1.0f;
  float iz = ((gzc + 1.0f) * 256.0f - 1.0f) * 0.5f;
  float z0f = floorf(iz);
  float wz = iz - z0f;
  int z0 = (int)z0f;

  // stage the two z-slices (zero-fill out-of-range -> implements z mask)
#pragma unroll
  for (int sl = 0; sl < 2; ++sl) {
    int z = z0 + sl;
    if (z >= 0 && z < 256) {  // block-uniform branch
      const float4* src = (const float4*)(fm + ((size_t)b * 256 + z) * 4096);
      for (int i = threadIdx.x; i < 1024; i += 256) {
        float4 v = src[i];
        int e = i << 2;
        int y = e >> 6, x0 = e & 63;
        int m = y & 31;
        int rb = y << 6;
        sm[sl][rb + ((x0 + 0) ^ m)] = v.x;
        sm[sl][rb + ((x0 + 1) ^ m)] = v.y;
        sm[sl][rb + ((x0 + 2) ^ m)] = v.z;
        sm[sl][rb + ((x0 + 3) ^ m)] = v.w;
      }
    } else {
      for (int i = threadIdx.x; i < 4096; i += 256) sm[sl][i] = 0.0f;
    }
  }

  // per-(b,d) params (uniform loads, L1 broadcast)
  float sc = par_ws[bd];
  float co = par_ws[1024 + bd];
  float si = par_ws[2048 + bd];
  float t0 = par_ws[3072 + bd];
  float t1 = par_ws[4096 + bd];
  __syncthreads();

  float wz1 = wz, wz0 = 1.0f - wz;
  float* outp = out + (size_t)bd * 4096;

#pragma unroll
  for (int j = 0; j < 4; ++j) {
    int e0 = (j << 10) + (threadIdx.x << 2);  // 4 consecutive elements per thread
    int h = e0 >> 6;
    int w0 = e0 & 63;
    float gy = 2.0f * (h * (1.0f / 63.0f)) - 1.0f;
    float rr[4];
#pragma unroll
    for (int q = 0; q < 4; ++q) {
      int w = w0 + q;
      float gx = 2.0f * (w * (1.0f / 63.0f)) - 1.0f;
      float tx = (co * gx - si * gy) * sc + t0;
      float ty = (si * gx + co * gy) * sc + t1;
      float ix = ((tx + 1.0f) * 64.0f - 1.0f) * 0.5f;
      float iy = ((ty + 1.0f) * 64.0f - 1.0f) * 0.5f;
      float x0f = floorf(ix), y0f = floorf(iy);
      float wx = ix - x0f, wy = iy - y0f;
      int xi = (int)x0f, yi = (int)y0f;
      float acc0 = 0.0f, acc1 = 0.0f;
#pragma unroll
      for (int dy = 0; dy < 2; ++dy) {
        int yy = yi + dy;
        float wyc = dy ? wy : (1.0f - wy);
        bool yok = ((unsigned)yy) < 64u;
        int yc = yy & 63;  // safe in-range addr; weight is masked if OOB
        int m = yc & 31;
        int rb = yc << 6;
#pragma unroll
        for (int dx = 0; dx < 2; ++dx) {
          int xx = xi + dx;
          bool ok = yok && (((unsigned)xx) < 64u);
          int xc = xx & 63;
          float wgt = (dx ? wx : (1.0f - wx)) * wyc;
          wgt = ok ? wgt : 0.0f;
          int addr = rb + (xc ^ m);
          acc0 = fmaf(sm[0][addr], wgt, acc0);
          acc1 = fmaf(sm[1][addr], wgt, acc1);
        }
      }
      rr[q] = wz0 * acc0 + wz1 * acc1;
    }
    float4 res;
    res.x = rr[0]; res.y = rr[1]; res.z = rr[2]; res.w = rr[3];
    ((float4*)outp)[(j << 8) + threadIdx.x] = res;
  }
}

extern "C" void kernel_launch(void* const* d_in, const int* in_sizes, int n_in,
                              void* d_out, int out_size, void* d_ws, size_t ws_size,
                              hipStream_t stream) {
  const float* fm        = (const float*)d_in[0];  // (4,256,64,64)
  const float* para_code = (const float*)d_in[1];  // (4,256)
  const float* W_c       = (const float*)d_in[2];  // (256,256)
  const float* b_c       = (const float*)d_in[3];  // (256,)
  const float* W_s       = (const float*)d_in[4];  // (256,256)
  const float* b_s       = (const float*)d_in[5];  // (256,)
  const float* W_r       = (const float*)d_in[6];  // (256,256)
  const float* b_r       = (const float*)d_in[7];  // (256,)
  const float* W_t       = (const float*)d_in[8];  // (256,512)
  const float* b_t       = (const float*)d_in[9];  // (512,)
  float* out = (float*)d_out;

  float* p_ws   = (float*)d_ws;   // 1024 floats
  float* par_ws = p_ws + 1024;    // 5*1024 floats

  mlp_p_kernel<<<16, 64, 0, stream>>>(para_code, W_c, b_c, p_ws);
  mlp_heads_kernel<<<16, 64, 0, stream>>>(p_ws, W_s, b_s, W_r, b_r, W_t, b_t, par_ws);
  warp_sample_kernel<<<1024, 256, 0, stream>>>(fm, par_ws, out);
}

// Round 2
// 111.444 us; speedup vs baseline: 1.2694x; 1.2694x over previous
//
#include <hip/hip_runtime.h>
#include <math.h>

#define PI_F 3.14159f

// One fused kernel: 512 blocks = (b in 0..3) x (dd in 0..127), 256 threads.
// Each block handles output planes d0=2*dd and d0+1 for batch b:
//   1. prefetch 3 z-slices (48KB) of the feature map into registers (HBM loads in flight)
//   2. redundant tiny MLP: p = relu(pc @ W_c + b_c)  (W_c from L2, coalesced)
//   3. heads: scale/cos/sin/t0/t1 for both planes (block reduce)
//   4. write slices to LDS (XOR bank swizzle), barrier
//   5. trilinear sample 2 planes x 4096 points
__global__ __launch_bounds__(256, 2) void adaat_fused_kernel(
    const float* __restrict__ fm,
    const float* __restrict__ para_code,
    const float* __restrict__ W_c, const float* __restrict__ b_c,
    const float* __restrict__ W_s, const float* __restrict__ b_s,
    const float* __restrict__ W_r, const float* __restrict__ b_r,
    const float* __restrict__ W_t, const float* __restrict__ b_t,
    float* __restrict__ out) {
  const int bid = blockIdx.x;
  const int b = bid >> 7;
  const int d0 = (bid & 127) << 1;
  const int d1 = d0 + 1;
  const int tid = threadIdx.x;

  __shared__ float sm[3 * 4096];   // 3 z-slices, XOR-swizzled
  __shared__ float p_l[256];
  __shared__ float red[4][8];
  __shared__ float prm[2][5];      // per plane: sc, cos, sin, t0, t1

  // ---- z geometry (exact reference formula sequence) ----
  float gz0 = 2.0f * (d0 * (1.0f / 255.0f)) - 1.0f;
  float izA = ((gz0 + 1.0f) * 256.0f - 1.0f) * 0.5f;
  float z0fA = floorf(izA);
  float wzA = izA - z0fA;
  int zA = (int)z0fA;
  float gz1 = 2.0f * (d1 * (1.0f / 255.0f)) - 1.0f;
  float izB = ((gz1 + 1.0f) * 256.0f - 1.0f) * 0.5f;
  float z0fB = floorf(izB);
  float wzB = izB - z0fB;
  int zB = (int)z0fB;
  const int zmin = zA;
  int slB = zB - zA;
  if (slB > 1) slB = 1;  // provably 0/1 for even d0; guard vs LDS OOB

  // ---- 1. prefetch 3 slices into registers (issued before MLP) ----
  float4 pre[3][4];
  const float4* fmb = (const float4*)(fm + ((size_t)b << 20));  // b*256*4096
#pragma unroll
  for (int s = 0; s < 3; ++s) {
    int z = zmin + s;
    if ((unsigned)z < 256u) {  // block-uniform branch
      const float4* src = fmb + ((size_t)z << 10);
#pragma unroll
      for (int i = 0; i < 4; ++i) pre[s][i] = src[(i << 8) + tid];
    } else {
#pragma unroll
      for (int i = 0; i < 4; ++i) pre[s][i] = make_float4(0.f, 0.f, 0.f, 0.f);
    }
  }

  // ---- 2. p = relu(pc @ W_c + b_c); pc reads are block-uniform (scalar) ----
  const float* pc = para_code + (b << 8);
  float acc = b_c[tid];
#pragma unroll 8
  for (int k = 0; k < 256; ++k) acc = fmaf(pc[k], W_c[(k << 8) + tid], acc);
  p_l[tid] = fmaxf(acc, 0.0f);

  // ---- 4a. write prefetched slices to LDS with XOR swizzle ----
#pragma unroll
  for (int s = 0; s < 3; ++s) {
    float* smb = sm + (s << 12);
#pragma unroll
    for (int i = 0; i < 4; ++i) {
      int e = ((i << 8) + tid) << 2;
      int y = e >> 6, x0 = e & 63;
      int m = y & 31, rb = y << 6;
      float4 v = pre[s][i];
      smb[rb + ((x0 + 0) ^ m)] = v.x;
      smb[rb + ((x0 + 1) ^ m)] = v.y;
      smb[rb + ((x0 + 2) ^ m)] = v.z;
      smb[rb + ((x0 + 3) ^ m)] = v.w;
    }
  }
  __syncthreads();  // covers p_l and sm

  // ---- 3. heads: 8 dot-products (2 planes x {s,r,t0,t1}) ----
  {
    float pk = p_l[tid];
    float2 ws = *(const float2*)(W_s + (tid << 8) + d0);
    float2 wr = *(const float2*)(W_r + (tid << 8) + d0);
    float4 wt = *(const float4*)(W_t + (tid << 9) + (d0 << 1));
    float v0 = pk * ws.x, v1 = pk * ws.y;   // s0, s1
    float v2 = pk * wr.x, v3 = pk * wr.y;   // r0, r1
    float v4 = pk * wt.x, v5 = pk * wt.z;   // ta0, ta1
    float v6 = pk * wt.y, v7 = pk * wt.w;   // tb0, tb1
#pragma unroll
    for (int off = 32; off > 0; off >>= 1) {
      v0 += __shfl_xor(v0, off);
      v1 += __shfl_xor(v1, off);
      v2 += __shfl_xor(v2, off);
      v3 += __shfl_xor(v3, off);
      v4 += __shfl_xor(v4, off);
      v5 += __shfl_xor(v5, off);
      v6 += __shfl_xor(v6, off);
      v7 += __shfl_xor(v7, off);
    }
    int wv = tid >> 6;
    if ((tid & 63) == 0) {
      red[wv][0] = v0; red[wv][1] = v1; red[wv][2] = v2; red[wv][3] = v3;
      red[wv][4] = v4; red[wv][5] = v5; red[wv][6] = v6; red[wv][7] = v7;
    }
  }
  __syncthreads();
  if (tid < 8) {
    float v = red[0][tid] + red[1][tid] + red[2][tid] + red[3][tid];
    int pl = tid & 1;
    int dsel = d0 + pl;
    int typ = tid >> 1;  // 0:scale 1:rot 2:t0 3:t1
    if (typ == 0) {
      v += b_s[dsel];
      prm[pl][0] = 2.0f / (1.0f + expf(-v));
    } else if (typ == 1) {
      v += b_r[dsel];
      float ang = tanhf(v) * PI_F;
      prm[pl][1] = cosf(ang);
      prm[pl][2] = sinf(ang);
    } else if (typ == 2) {
      v += b_t[2 * dsel];
      prm[pl][3] = tanhf(v);
    } else {
      v += b_t[2 * dsel + 1];
      prm[pl][4] = tanhf(v);
    }
  }
  __syncthreads();

  // ---- 5. trilinear sample, 2 planes x 16 points/thread ----
#pragma unroll
  for (int pl = 0; pl < 2; ++pl) {
    const float sc = prm[pl][0];
    const float co = prm[pl][1];
    const float si = prm[pl][2];
    const float t0 = prm[pl][3];
    const float t1 = prm[pl][4];
    const float wz = pl ? wzB : wzA;
    const float wzl0 = 1.0f - wz, wzl1 = wz;
    const float* smA = sm + ((pl ? slB : 0) << 12);
    const float* smB = smA + 4096;
    float* outp = out + (((size_t)(b << 8) + d0 + pl) << 12);

#pragma unroll
    for (int j = 0; j < 4; ++j) {
      int e0 = (j << 10) + (tid << 2);
      int h = e0 >> 6;
      int w0 = e0 & 63;
      float gy = 2.0f * (h * (1.0f / 63.0f)) - 1.0f;
      float rr[4];
#pragma unroll
      for (int q = 0; q < 4; ++q) {
        int w = w0 + q;
        float gx = 2.0f * (w * (1.0f / 63.0f)) - 1.0f;
        float tx = (co * gx - si * gy) * sc + t0;
        float ty = (si * gx + co * gy) * sc + t1;
        float ix = ((tx + 1.0f) * 64.0f - 1.0f) * 0.5f;
        float iy = ((ty + 1.0f) * 64.0f - 1.0f) * 0.5f;
        float x0f = floorf(ix), y0f = floorf(iy);
        float wx = ix - x0f, wy = iy - y0f;
        int xi = (int)x0f, yi = (int)y0f;
        float acc0 = 0.0f, acc1 = 0.0f;
#pragma unroll
        for (int dy = 0; dy < 2; ++dy) {
          int yy = yi + dy;
          float wyc = dy ? wy : (1.0f - wy);
          bool yok = ((unsigned)yy) < 64u;
          int yc = yy & 63;
          int m = yc & 31;
          int rb = yc << 6;
#pragma unroll
          for (int dx = 0; dx < 2; ++dx) {
            int xx = xi + dx;
            bool ok = yok && (((unsigned)xx) < 64u);
            int xc = xx & 63;
            float wgt = (dx ? wx : (1.0f - wx)) * wyc;
            wgt = ok ? wgt : 0.0f;
            int addr = rb + (xc ^ m);
            acc0 = fmaf(smA[addr], wgt, acc0);
            acc1 = fmaf(smB[addr], wgt, acc1);
          }
        }
        rr[q] = wzl0 * acc0 + wzl1 * acc1;
      }
      float4 res;
      res.x = rr[0]; res.y = rr[1]; res.z = rr[2]; res.w = rr[3];
      ((float4*)outp)[(j << 8) + tid] = res;
    }
  }
}

extern "C" void kernel_launch(void* const* d_in, const int* in_sizes, int n_in,
                              void* d_out, int out_size, void* d_ws, size_t ws_size,
                              hipStream_t stream) {
  const float* fm        = (const float*)d_in[0];  // (4,256,64,64)
  const float* para_code = (const float*)d_in[1];  // (4,256)
  const float* W_c       = (const float*)d_in[2];  // (256,256)
  const float* b_c       = (const float*)d_in[3];  // (256,)
  const float* W_s       = (const float*)d_in[4];  // (256,256)
  const float* b_s       = (const float*)d_in[5];  // (256,)
  const float* W_r       = (const float*)d_in[6];  // (256,256)
  const float* b_r       = (const float*)d_in[7];  // (256,)
  const float* W_t       = (const float*)d_in[8];  // (256,512)
  const float* b_t       = (const float*)d_in[9];  // (512,)
  float* out = (float*)d_out;

  adaat_fused_kernel<<<512, 256, 0, stream>>>(
      fm, para_code, W_c, b_c, W_s, b_s, W_r, b_r, W_t, b_t, out);
}

// Round 3
// 102.542 us; speedup vs baseline: 1.3796x; 1.0868x over previous
//
#include <hip/hip_runtime.h>
#include <math.h>

#define PI_F 3.14159f
#define SLICE 4160  // 64 rows x (64+1 pad) floats

// One fused kernel: 512 blocks = (b in 0..3) x (dd in 0..127), 256 threads.
// Block handles output planes d0=2*dd, d0+1 of batch b. Steps:
//   1. stream 3 z-slices HBM -> LDS (padded stride-65 layout)
//   2. redundant p = relu(pc @ W_c + b_c): split-K over 4 waves, float4 loads
//   3. heads scale/cos/sin/t0/t1 (wave shuffle + LDS reduce)
//   4. trilinear sample: constant-offset taps {0,1,65,66} -> ds_read2_b32 pairs
__global__ __launch_bounds__(256, 2) void adaat_fused_kernel(
    const float* __restrict__ fm,
    const float* __restrict__ para_code,
    const float* __restrict__ W_c, const float* __restrict__ b_c,
    const float* __restrict__ W_s, const float* __restrict__ b_s,
    const float* __restrict__ W_r, const float* __restrict__ b_r,
    const float* __restrict__ W_t, const float* __restrict__ b_t,
    float* __restrict__ out) {
  const int bid = blockIdx.x;
  const int b = bid >> 7;
  const int d0 = (bid & 127) << 1;
  const int d1 = d0 + 1;
  const int tid = threadIdx.x;

  __shared__ float sm[3 * SLICE];   // 48.75 KB
  __shared__ float redp[4][256];    // GEMV split-K partials (4 KB)
  __shared__ float red[4][8];
  __shared__ float prm[2][5];       // per plane: sc, cos, sin, t0, t1

  // ---- z geometry (exact reference formula sequence) ----
  float gz0 = 2.0f * (d0 * (1.0f / 255.0f)) - 1.0f;
  float izA = ((gz0 + 1.0f) * 256.0f - 1.0f) * 0.5f;
  float z0fA = floorf(izA);
  float wzA = izA - z0fA;
  int zA = (int)z0fA;
  float gz1 = 2.0f * (d1 * (1.0f / 255.0f)) - 1.0f;
  float izB = ((gz1 + 1.0f) * 256.0f - 1.0f) * 0.5f;
  float z0fB = floorf(izB);
  float wzB = izB - z0fB;
  int zB = (int)z0fB;
  int slB = zB - zA;            // == 1 for all even-d0 pairs (proven; guard anyway)
  if (slB > 1) slB = 1;
  if (slB < 0) slB = 0;

  // ---- 1. stream 3 slices into padded LDS ----
  const float4* fmb = (const float4*)(fm + ((size_t)b << 20));
#pragma unroll
  for (int s = 0; s < 3; ++s) {
    int z = zA + s;
    float* smb = sm + s * SLICE;
    if ((unsigned)z < 256u) {   // block-uniform branch
      const float4* src = fmb + ((size_t)z << 10);
#pragma unroll
      for (int i = 0; i < 4; ++i) {
        int idx = (i << 8) + tid;
        float4 v = src[idx];
        int e = idx << 2;
        int y = e >> 6, x0 = e & 63;
        int a = y * 65 + x0;
        smb[a] = v.x; smb[a + 1] = v.y; smb[a + 2] = v.z; smb[a + 3] = v.w;
      }
    } else {
      for (int i = tid; i < SLICE; i += 256) smb[i] = 0.0f;
    }
  }

  // ---- 2. GEMV p = relu(pc @ W_c + b_c), split-K over waves ----
  {
    const int wv = tid >> 6, ln = tid & 63;
    const float* pcb = para_code + (b << 8);
    float pcv = pcb[(wv << 6) | ln];  // lane ln holds pc[k0+ln]
    float4 a4 = make_float4(0.f, 0.f, 0.f, 0.f);
#pragma unroll
    for (int kk = 0; kk < 64; ++kk) {
      float pk = __int_as_float(
          __builtin_amdgcn_readlane(__float_as_int(pcv), kk));
      const float4* Wrow = (const float4*)(W_c + (((wv << 6) + kk) << 8));
      float4 w4 = Wrow[ln];
      a4.x = fmaf(pk, w4.x, a4.x);
      a4.y = fmaf(pk, w4.y, a4.y);
      a4.z = fmaf(pk, w4.z, a4.z);
      a4.w = fmaf(pk, w4.w, a4.w);
    }
    ((float4*)&redp[wv][0])[ln] = a4;
  }
  __syncthreads();  // covers sm, redp

  // ---- 3. heads: 8 dot-products (2 planes x {s,r,t0,t1}) ----
  {
    float pk = fmaxf(redp[0][tid] + redp[1][tid] + redp[2][tid] +
                         redp[3][tid] + b_c[tid],
                     0.0f);
    float2 ws = *(const float2*)(W_s + (tid << 8) + d0);
    float2 wr = *(const float2*)(W_r + (tid << 8) + d0);
    float4 wt = *(const float4*)(W_t + (tid << 9) + (d0 << 1));
    float v0 = pk * ws.x, v1 = pk * ws.y;
    float v2 = pk * wr.x, v3 = pk * wr.y;
    float v4 = pk * wt.x, v5 = pk * wt.z;
    float v6 = pk * wt.y, v7 = pk * wt.w;
#pragma unroll
    for (int off = 32; off > 0; off >>= 1) {
      v0 += __shfl_xor(v0, off);
      v1 += __shfl_xor(v1, off);
      v2 += __shfl_xor(v2, off);
      v3 += __shfl_xor(v3, off);
      v4 += __shfl_xor(v4, off);
      v5 += __shfl_xor(v5, off);
      v6 += __shfl_xor(v6, off);
      v7 += __shfl_xor(v7, off);
    }
    int wv = tid >> 6;
    if ((tid & 63) == 0) {
      red[wv][0] = v0; red[wv][1] = v1; red[wv][2] = v2; red[wv][3] = v3;
      red[wv][4] = v4; red[wv][5] = v5; red[wv][6] = v6; red[wv][7] = v7;
    }
  }
  __syncthreads();
  if (tid < 8) {
    float v = red[0][tid] + red[1][tid] + red[2][tid] + red[3][tid];
    int pl = tid & 1;
    int dsel = d0 + pl;
    int typ = tid >> 1;  // 0:scale 1:rot 2:t0 3:t1
    if (typ == 0) {
      v += b_s[dsel];
      prm[pl][0] = 2.0f / (1.0f + expf(-v));
    } else if (typ == 1) {
      v += b_r[dsel];
      float ang = tanhf(v) * PI_F;
      prm[pl][1] = cosf(ang);
      prm[pl][2] = sinf(ang);
    } else if (typ == 2) {
      v += b_t[2 * dsel];
      prm[pl][3] = tanhf(v);
    } else {
      v += b_t[2 * dsel + 1];
      prm[pl][4] = tanhf(v);
    }
  }
  __syncthreads();

  // ---- 4. trilinear sample, 2 planes x 16 points/thread ----
#pragma unroll
  for (int pl = 0; pl < 2; ++pl) {
    const float sc = prm[pl][0];
    const float co = prm[pl][1];
    const float si = prm[pl][2];
    const float t0 = prm[pl][3];
    const float t1 = prm[pl][4];
    const float wz = pl ? wzB : wzA;
    const float wzl0 = 1.0f - wz, wzl1 = wz;
    const float* smA = sm + ((pl ? slB : 0) * SLICE);
    const float* smB = smA + SLICE;
    float* outp = out + (((size_t)(b << 8) + d0 + pl) << 12);

#pragma unroll
    for (int j = 0; j < 4; ++j) {
      int e0 = (j << 10) + (tid << 2);
      int h = e0 >> 6;
      int w0 = e0 & 63;
      float gy = 2.0f * (h * (1.0f / 63.0f)) - 1.0f;
      float rr[4];
#pragma unroll
      for (int q = 0; q < 4; ++q) {
        int w = w0 + q;
        float gx = 2.0f * (w * (1.0f / 63.0f)) - 1.0f;
        float tx = (co * gx - si * gy) * sc + t0;
        float ty = (si * gx + co * gy) * sc + t1;
        float ix = ((tx + 1.0f) * 64.0f - 1.0f) * 0.5f;
        float iy = ((ty + 1.0f) * 64.0f - 1.0f) * 0.5f;
        float x0f = floorf(ix), y0f = floorf(iy);
        float wx = ix - x0f, wy = iy - y0f;
        int xi = (int)x0f, yi = (int)y0f;
        // base clamped so taps {0,1,65,66} stay in-bounds; weights per slot
        int bx = min(max(xi, 0), 62);
        int by = min(max(yi, 0), 62);
        float sx0 = (bx == xi) ? (1.0f - wx) : ((bx == xi + 1) ? wx : 0.0f);
        float sx1 = (bx == xi) ? wx : ((bx + 1 == xi) ? (1.0f - wx) : 0.0f);
        float sy0 = (by == yi) ? (1.0f - wy) : ((by == yi + 1) ? wy : 0.0f);
        float sy1 = (by == yi) ? wy : ((by + 1 == yi) ? (1.0f - wy) : 0.0f);
        float w00 = sy0 * sx0, w01 = sy0 * sx1;
        float w10 = sy1 * sx0, w11 = sy1 * sx1;
        int base = by * 65 + bx;
        float accA = fmaf(smA[base], w00,
                     fmaf(smA[base + 1], w01,
                     fmaf(smA[base + 65], w10, smA[base + 66] * w11)));
        float accB = fmaf(smB[base], w00,
                     fmaf(smB[base + 1], w01,
                     fmaf(smB[base + 65], w10, smB[base + 66] * w11)));
        rr[q] = fmaf(wzl0, accA, wzl1 * accB);
      }
      float4 res;
      res.x = rr[0]; res.y = rr[1]; res.z = rr[2]; res.w = rr[3];
      ((float4*)outp)[(j << 8) + tid] = res;
    }
  }
}

extern "C" void kernel_launch(void* const* d_in, const int* in_sizes, int n_in,
                              void* d_out, int out_size, void* d_ws, size_t ws_size,
                              hipStream_t stream) {
  const float* fm        = (const float*)d_in[0];  // (4,256,64,64)
  const float* para_code = (const float*)d_in[1];  // (4,256)
  const float* W_c       = (const float*)d_in[2];  // (256,256)
  const float* b_c       = (const float*)d_in[3];  // (256,)
  const float* W_s       = (const float*)d_in[4];  // (256,256)
  const float* b_s       = (const float*)d_in[5];  // (256,)
  const float* W_r       = (const float*)d_in[6];  // (256,256)
  const float* b_r       = (const float*)d_in[7];  // (256,)
  const float* W_t       = (const float*)d_in[8];  // (256,512)
  const float* b_t       = (const float*)d_in[9];  // (512,)
  float* out = (float*)d_out;

  adaat_fused_kernel<<<512, 256, 0, stream>>>(
      fm, para_code, W_c, b_c, W_s, b_s, W_r, b_r, W_t, b_t, out);
}

// Round 5
// 102.250 us; speedup vs baseline: 1.3835x; 1.0029x over previous
//
#include <hip/hip_runtime.h>
#include <math.h>

#define PI_F 3.14159f
#define STRD 69            // row stride: 66 used cols (-1..65 -> slots 0..66) + pad
#define SLICE3 (67 * 69)   // 67 rows (y=-1..65) * stride

// One fused kernel: 512 blocks = (b in 0..3) x (dd in 0..127), 256 threads.
// Block handles output planes d0=2*dd, d0+1 of batch b:
//   1. prefetch 3 z-slices HBM -> regs (in flight during GEMV)
//   2. zero LDS guard ring
//   3. p = relu(pc @ W_c + b_c), split-K over 4 waves, float4 loads
//   4. heads scale/cos/sin/t0/t1 (shuffle + LDS reduce)
//   5. ds_write slices into guard-ring layout; barrier
//   6. bilinear-x-z sample: med3-clamped base + guard ring -> 3 VALU/axis,
//      taps {0,1,69,70} -> 2x ds_read2_b32 per slice
__global__ __launch_bounds__(256, 2) void adaat_fused_kernel(
    const float* __restrict__ fm,
    const float* __restrict__ para_code,
    const float* __restrict__ W_c, const float* __restrict__ b_c,
    const float* __restrict__ W_s, const float* __restrict__ b_s,
    const float* __restrict__ W_r, const float* __restrict__ b_r,
    const float* __restrict__ W_t, const float* __restrict__ b_t,
    float* __restrict__ out) {
  const int bid = blockIdx.x;
  const int b = bid >> 7;
  const int d0 = (bid & 127) << 1;
  const int d1 = d0 + 1;
  const int tid = threadIdx.x;

  __shared__ float sm[3 * SLICE3];  // 54.2 KB, guard-ring padded slices
  __shared__ float redp[4][256];    // GEMV split-K partials
  __shared__ float red[4][8];
  __shared__ float prm[2][5];       // per plane: sc, cos, sin, t0, t1

  // ---- z geometry (exact reference formula sequence) ----
  float gz0 = 2.0f * (d0 * (1.0f / 255.0f)) - 1.0f;
  float izA = ((gz0 + 1.0f) * 256.0f - 1.0f) * 0.5f;
  float z0fA = floorf(izA);
  float wzA = izA - z0fA;
  int zA = (int)z0fA;
  float gz1 = 2.0f * (d1 * (1.0f / 255.0f)) - 1.0f;
  float izB = ((gz1 + 1.0f) * 256.0f - 1.0f) * 0.5f;
  float z0fB = floorf(izB);
  float wzB = izB - z0fB;
  int zB = (int)z0fB;
  int slB = zB - zA;  // ==1 for all even d0 (proven); guard anyway
  if (slB > 1) slB = 1;
  if (slB < 0) slB = 0;

  // ---- 1. prefetch 3 slices into registers (issued before GEMV) ----
  float4 pre[3][4];
  const float4* fmb = (const float4*)(fm + ((size_t)b << 20));
#pragma unroll
  for (int s = 0; s < 3; ++s) {
    int z = zA + s;
    if ((unsigned)z < 256u) {  // block-uniform branch
      const float4* src = fmb + ((size_t)z << 10);
#pragma unroll
      for (int i = 0; i < 4; ++i) pre[s][i] = src[(i << 8) + tid];
    } else {
#pragma unroll
      for (int i = 0; i < 4; ++i) pre[s][i] = make_float4(0.f, 0.f, 0.f, 0.f);
    }
  }

  // ---- 2. zero guard ring (no vmcnt dependency; overlaps loads) ----
#pragma unroll
  for (int s = 0; s < 3; ++s) {
    float* smb = sm + s * SLICE3;
    if (tid < STRD) {  // guard rows r=0 (y=-1), r=65, r=66
      smb[tid] = 0.0f;
      smb[65 * STRD + tid] = 0.0f;
      smb[66 * STRD + tid] = 0.0f;
    }
    // guard cols of interior rows r=1..64: slots 0,65,66 (+67 harmless)
    int r = 1 + (tid >> 2);
    int q = tid & 3;
    int c = q ? (64 + q) : 0;
    smb[r * STRD + c] = 0.0f;
  }

  // ---- 3. GEMV p = relu(pc @ W_c + b_c), split-K over waves ----
  {
    const int wv = tid >> 6, ln = tid & 63;
    const float* pcb = para_code + (b << 8);
    float pcv = pcb[(wv << 6) | ln];
    float4 a4 = make_float4(0.f, 0.f, 0.f, 0.f);
#pragma unroll
    for (int kk = 0; kk < 64; ++kk) {
      float pk = __int_as_float(
          __builtin_amdgcn_readlane(__float_as_int(pcv), kk));
      const float4* Wrow = (const float4*)(W_c + (((wv << 6) + kk) << 8));
      float4 w4 = Wrow[ln];
      a4.x = fmaf(pk, w4.x, a4.x);
      a4.y = fmaf(pk, w4.y, a4.y);
      a4.z = fmaf(pk, w4.z, a4.z);
      a4.w = fmaf(pk, w4.w, a4.w);
    }
    ((float4*)&redp[wv][0])[ln] = a4;
  }

  // ---- 5a. write interior of slices (loads have drained under GEMV) ----
#pragma unroll
  for (int s = 0; s < 3; ++s) {
    float* smb = sm + s * SLICE3;
#pragma unroll
    for (int i = 0; i < 4; ++i) {
      int e = ((i << 8) + tid) << 2;
      int y = e >> 6, x0 = e & 63;
      int a = (y + 1) * STRD + x0 + 1;
      float4 v = pre[s][i];
      smb[a] = v.x; smb[a + 1] = v.y; smb[a + 2] = v.z; smb[a + 3] = v.w;
    }
  }
  __syncthreads();  // covers sm, redp

  // ---- 4. heads: 8 dot-products (2 planes x {s,r,t0,t1}) ----
  {
    float pk = fmaxf(redp[0][tid] + redp[1][tid] + redp[2][tid] +
                         redp[3][tid] + b_c[tid],
                     0.0f);
    float2 ws = *(const float2*)(W_s + (tid << 8) + d0);
    float2 wr = *(const float2*)(W_r + (tid << 8) + d0);
    float4 wt = *(const float4*)(W_t + (tid << 9) + (d0 << 1));
    float v0 = pk * ws.x, v1 = pk * ws.y;
    float v2 = pk * wr.x, v3 = pk * wr.y;
    float v4 = pk * wt.x, v5 = pk * wt.z;
    float v6 = pk * wt.y, v7 = pk * wt.w;
#pragma unroll
    for (int off = 32; off > 0; off >>= 1) {
      v0 += __shfl_xor(v0, off);
      v1 += __shfl_xor(v1, off);
      v2 += __shfl_xor(v2, off);
      v3 += __shfl_xor(v3, off);
      v4 += __shfl_xor(v4, off);
      v5 += __shfl_xor(v5, off);
      v6 += __shfl_xor(v6, off);
      v7 += __shfl_xor(v7, off);
    }
    int wv = tid >> 6;
    if ((tid & 63) == 0) {
      red[wv][0] = v0; red[wv][1] = v1; red[wv][2] = v2; red[wv][3] = v3;
      red[wv][4] = v4; red[wv][5] = v5; red[wv][6] = v6; red[wv][7] = v7;
    }
  }
  __syncthreads();
  if (tid < 8) {
    float v = red[0][tid] + red[1][tid] + red[2][tid] + red[3][tid];
    int pl = tid & 1;
    int dsel = d0 + pl;
    int typ = tid >> 1;  // 0:scale 1:rot 2:t0 3:t1
    if (typ == 0) {
      v += b_s[dsel];
      prm[pl][0] = 2.0f / (1.0f + expf(-v));
    } else if (typ == 1) {
      v += b_r[dsel];
      float ang = tanhf(v) * PI_F;
      prm[pl][1] = cosf(ang);
      prm[pl][2] = sinf(ang);
    } else if (typ == 2) {
      v += b_t[2 * dsel];
      prm[pl][3] = tanhf(v);
    } else {
      v += b_t[2 * dsel + 1];
      prm[pl][4] = tanhf(v);
    }
  }
  __syncthreads();

  // ---- 6. sample, 2 planes x 16 points/thread, incremental coords ----
  const float dgx = 2.0f / 63.0f;
  const int w0 = (tid & 15) << 2;   // constant across j
  const int h0 = tid >> 4;
  const float gx0 = w0 * dgx - 1.0f;

#pragma unroll
  for (int pl = 0; pl < 2; ++pl) {
    const float sc = prm[pl][0];
    const float co = prm[pl][1];
    const float si = prm[pl][2];
    const float t0 = prm[pl][3];
    const float t1 = prm[pl][4];
    const float wz = pl ? wzB : wzA;
    const float wzl0 = 1.0f - wz, wzl1 = wz;
    const float* smA = sm + ((pl ? slB : 0) * SLICE3);
    const float* smB = smA + SLICE3;
    float* outp = out + (((size_t)(b << 8) + d0 + pl) << 12);

    // ix = tx*32 + 31.5 with tx = (co*gx - si*gy)*sc + t0
    const float co32 = co * sc * 32.0f;
    const float si32 = si * sc * 32.0f;
    const float stx = co32 * dgx;   // d(ix)/dw
    const float sty = si32 * dgx;   // d(iy)/dw
    const float ixw = fmaf(co32, gx0, fmaf(t0, 32.0f, 31.5f));
    const float iyw = fmaf(si32, gx0, fmaf(t1, 32.0f, 31.5f));

#pragma unroll
    for (int j = 0; j < 4; ++j) {
      int h = (j << 4) + h0;
      float gy = h * dgx - 1.0f;
      float ix = fmaf(-si32, gy, ixw);
      float iy = fmaf(co32, gy, iyw);
      float rr[4];
#pragma unroll
      for (int q = 0; q < 4; ++q) {
        float x0f = floorf(ix), y0f = floorf(iy);
        float wx = ix - x0f, wy = iy - y0f;
        int xi = (int)x0f, yi = (int)y0f;
        int bx = min(max(xi, -1), 64);     // v_med3_i32
        int by = min(max(yi, -1), 64);
        float wxe = (bx == xi) ? wx : 0.0f;
        float wye = (by == yi) ? wy : 0.0f;
        float w11 = wye * wxe;
        float w10 = wye - w11;
        float w01 = wxe - w11;
        float w00 = (1.0f - wye) - w01;
        int base = (by + 1) * STRD + bx + 1;
        float accA = fmaf(smA[base], w00,
                     fmaf(smA[base + 1], w01,
                     fmaf(smA[base + STRD], w10, smA[base + STRD + 1] * w11)));
        float accB = fmaf(smB[base], w00,
                     fmaf(smB[base + 1], w01,
                     fmaf(smB[base + STRD], w10, smB[base + STRD + 1] * w11)));
        rr[q] = fmaf(wzl0, accA, wzl1 * accB);
        ix += stx;
        iy += sty;
      }
      float4 res;
      res.x = rr[0]; res.y = rr[1]; res.z = rr[2]; res.w = rr[3];
      ((float4*)outp)[(j << 8) + (h0 << 4) + (w0 >> 2)] = res;
    }
  }
}

extern "C" void kernel_launch(void* const* d_in, const int* in_sizes, int n_in,
                              void* d_out, int out_size, void* d_ws, size_t ws_size,
                              hipStream_t stream) {
  const float* fm        = (const float*)d_in[0];  // (4,256,64,64)
  const float* para_code = (const float*)d_in[1];  // (4,256)
  const float* W_c       = (const float*)d_in[2];  // (256,256)
  const float* b_c       = (const float*)d_in[3];  // (256,)
  const float* W_s       = (const float*)d_in[4];  // (256,256)
  const float* b_s       = (const float*)d_in[5];  // (256,)
  const float* W_r       = (const float*)d_in[6];  // (256,256)
  const float* b_r       = (const float*)d_in[7];  // (256,)
  const float* W_t       = (const float*)d_in[8];  // (256,512)
  const float* b_t       = (const float*)d_in[9];  // (512,)
  float* out = (float*)d_out;

  adaat_fused_kernel<<<512, 256, 0, stream>>>(
      fm, para_code, W_c, b_c, W_s, b_s, W_r, b_r, W_t, b_t, out);
}